// Round 15
// baseline (243.968 us; speedup 1.0000x reference)
//
#include <hip/hip_runtime.h>
#include <hip/hip_bf16.h>

// Detect head: prep (fp32->bf16 convert + x transpose) then fused MFMA GEMM + decode.
// R15: persistent-ish multi-anchor blocks at 2 blocks/CU with exact counted-vmcnt
// pipelining across anchors (stores never drained):
//   - Block = 64px x 6 anchors. A [64][256] staged once (lvl1: half-K, restaged
//     per anchor-half with counted waits). B dbuf 2x[96][64] 12KB. Image 11KB
//     (two 32px epilogue halves). Bias in LDS. Total ~69KB -> 2 blocks/CU.
//   - Waits use per-wave exact outstanding-op counts (vmcnt retires in order),
//     so epilogue nt-stores stay in flight under the next anchor's compute.

typedef __attribute__((ext_vector_type(8))) short short8;
typedef __attribute__((ext_vector_type(4))) short short4v;
typedef __attribute__((ext_vector_type(4))) float f32x4;
typedef unsigned int u32;

__device__ __forceinline__ unsigned short f2bf(float f) {
    union { float f; unsigned u; } c; c.f = f;
    return (unsigned short)((c.u + 0x7fffu + ((c.u >> 16) & 1u)) >> 16);  // RTNE
}
__device__ __forceinline__ float sigm(float v) {
    return 1.0f / (1.0f + __expf(-v));
}
__device__ __forceinline__ void gload16(const void* g, void* l) {
    __builtin_amdgcn_global_load_lds(
        (const __attribute__((address_space(1))) u32*)g,
        (__attribute__((address_space(3))) u32*)l, 16, 0, 0);
}
__device__ __forceinline__ void waitv(int n) {
    switch (n) {
    case 0:  asm volatile("s_waitcnt vmcnt(0)" ::: "memory"); break;
    case 1:  asm volatile("s_waitcnt vmcnt(1)" ::: "memory"); break;
    case 2:  asm volatile("s_waitcnt vmcnt(2)" ::: "memory"); break;
    case 3:  asm volatile("s_waitcnt vmcnt(3)" ::: "memory"); break;
    case 4:  asm volatile("s_waitcnt vmcnt(4)" ::: "memory"); break;
    case 6:  asm volatile("s_waitcnt vmcnt(6)" ::: "memory"); break;
    case 7:  asm volatile("s_waitcnt vmcnt(7)" ::: "memory"); break;
    case 8:  asm volatile("s_waitcnt vmcnt(8)" ::: "memory"); break;
    default: asm volatile("s_waitcnt vmcnt(10)" ::: "memory"); break;
    }
    __builtin_amdgcn_sched_barrier(0);
}

#define OUT_CH 1548
#define NCHN   86
#define BPB    7925760   // per-batch output elements = 92160*86

// ---------------- prep kernels ----------------

__global__ void conv_w_kernel(const float* __restrict__ W0, unsigned short* __restrict__ Wb0,
                              const float* __restrict__ W1, unsigned short* __restrict__ Wb1) {
    int i = blockIdx.x * blockDim.x + threadIdx.x;
    if (i >= 297216) return;
    const float* W = W0;
    unsigned short* Wb = Wb0;
    if (i >= 99072) { W = W1; Wb = Wb1; i -= 99072; }
    const float4 f = ((const float4*)W)[i];
    short4v v;
    v[0] = (short)f2bf(f.x); v[1] = (short)f2bf(f.y);
    v[2] = (short)f2bf(f.z); v[3] = (short)f2bf(f.w);
    ((short4v*)Wb)[i] = v;
}

__global__ void transpose_x_kernel(const float* __restrict__ X, unsigned short* __restrict__ Xb,
                                   int C, int GG) {
    __shared__ float sT[64][65];
    const int p0 = blockIdx.x * 64;
    const int c0 = blockIdx.y * 64;
    const int b  = blockIdx.z;
    const int tid = threadIdx.x;
    const float* src = X + ((size_t)b * C + c0) * GG + p0;
    const int rc = tid >> 4;
    const int cp = (tid & 15) * 4;
    #pragma unroll
    for (int rr = 0; rr < 4; ++rr) {
        const int c = rc + rr * 16;
        const float4 f = *(const float4*)&src[(size_t)c * GG + cp];
        sT[c][cp + 0] = f.x; sT[c][cp + 1] = f.y;
        sT[c][cp + 2] = f.z; sT[c][cp + 3] = f.w;
    }
    __syncthreads();
    const int p  = tid >> 2;
    const int cg = (tid & 3) * 16;
    unsigned short u[16];
    #pragma unroll
    for (int k = 0; k < 16; ++k) u[k] = f2bf(sT[cg + k][p]);
    unsigned short* dst = Xb + ((size_t)b * GG + p0 + p) * C + c0 + cg;
    *(short8*)dst       = *(const short8*)&u[0];
    *(short8*)(dst + 8) = *(const short8*)&u[8];
}

// ---------------- main GEMM + decode ----------------

template<int LVL>
__device__ __forceinline__ void body(int v, char* smem,
    const unsigned short* __restrict__ Xb, const unsigned short* __restrict__ Wb,
    const float* __restrict__ bias, float* __restrict__ out)
{
    constexpr int C    = LVL ? 512 : 256;
    constexpr int GG   = LVL ? 1024 : 4096;
    constexpr int Gsh  = LVL ? 5 : 6;
    constexpr int KT   = LVL ? 8 : 4;
    constexpr int S    = 6 * KT;
    constexpr int LVOF = LVL ? 73728 : 0;
    const float sxy     = LVL ? 1.1f : 1.2f;
    const float sxy_off = (sxy - 1.0f) * 0.5f;
    const float sf      = LVL ? 16.0f : 8.0f;

    // LDS map
    unsigned short* sA = (unsigned short*)smem;            // 32768 B
    char* sB0   = smem + 32768;                            // 2 x 12288 B
    float* sImg = (float*)(smem + 57344);                  // 11008 B
    float* sBias= (float*)(smem + 68352);                  // 2064 B

    const int m   = v / 3;
    const int grp = v - m * 3;
    const int aBase = grp * 6;
    const int b  = m >> (LVL ? 4 : 6);
    const int p0 = (m & (LVL ? 15 : 63)) * 64;

    const int tid  = threadIdx.x;
    const int lane = tid & 63;
    const int wid  = tid >> 6;        // 0..7
    const int wm = wid >> 1;          // 0..3 : 16px slice
    const int wn = wid & 1;           // 0..1 : 48ch half
    const int lr  = lane & 15;
    const int kqb = (lane >> 4) << 4;
    const int rq  = (lane >> 4) * 4;
    const int swzR = (lr & 7) << 4;

    const unsigned short* __restrict__ Xp = Xb + ((size_t)b * GG + p0) * C;

    // staging consts
    const int rowInA = tid >> 5;                                        // 0..15
    const int colAe  = ((((tid & 31) << 4)) ^ ((rowInA & 7) << 4)) >> 1;
    const int rowInB = lane >> 3;                                       // 0..7
    const int colBe  = ((((lane & 7) << 4)) ^ ((rowInB & 7) << 4)) >> 1;

    auto stageA = [&](int h) {   // 4 loads/thread, [64][256] pitch 512B
        #pragma unroll
        for (int i = 0; i < 4; ++i)
            gload16(Xp + (size_t)(i * 16 + rowInA) * C + h * 256 + colAe,
                    smem + i * 8192 + tid * 16);
    };
    auto stageB = [&](int s) {   // waves 0-3: 2 loads, waves 4-7: 1 load
        const int ag = aBase + (s >> (LVL ? 3 : 2));
        const int k0 = (s & (KT - 1)) << 6;
        char* dst = sB0 + (s & 1) * 12288;
        {
            const int row = wid * 8 + rowInB;
            int grow = ag * NCHN + row;
            grow = grow > (OUT_CH - 1) ? (OUT_CH - 1) : grow;
            gload16(Wb + (size_t)grow * C + k0 + colBe, dst + wid * 1024);
        }
        if (wid < 4) {
            const int row = 64 + wid * 8 + rowInB;
            int grow = ag * NCHN + row;
            grow = grow > (OUT_CH - 1) ? (OUT_CH - 1) : grow;
            gload16(Wb + (size_t)grow * C + k0 + colBe, dst + 8192 + wid * 1024);
        }
    };

    f32x4 acc[3];
    #pragma unroll
    for (int j = 0; j < 3; ++j) acc[j] = f32x4{0.f, 0.f, 0.f, 0.f};

    auto compute = [&](int buf, int kt) {
        const char* bb = sB0 + buf * 12288;
        const int colbase = (kt & 3) << 7;
        #pragma unroll
        for (int kk = 0; kk < 2; ++kk) {
            const int cbA = (colbase + (kk << 6) + kqb) ^ swzR;
            const int cbB = (((kk << 6) + kqb)) ^ swzR;
            const int ra = wm * 16 + lr;
            const short8 af = *(const short8*)((const char*)sA + ra * 512 + cbA);
            short8 bfr[3];
            #pragma unroll
            for (int j = 0; j < 3; ++j) {
                const int rb = wn * 48 + j * 16 + lr;
                bfr[j] = *(const short8*)(bb + rb * 128 + cbB);
            }
            #pragma unroll
            for (int j = 0; j < 3; ++j)
                acc[j] = __builtin_amdgcn_mfma_f32_16x16x32_bf16(af, bfr[j], acc[j], 0, 0, 0);
        }
    };

    auto epilogue = [&](int aL) {
        const int ag = aBase + aL;
        const int shp  = ag / 6;
        const int angi = ag - shp * 6;
        const float aw = LVL ? ((shp == 0) ? 30.f : (shp == 1) ? 62.f : 59.f)
                             : ((shp == 0) ? 10.f : (shp == 1) ? 16.f : 33.f);
        const float ah = LVL ? ((shp == 0) ? 61.f : (shp == 1) ? 45.f : 119.f)
                             : ((shp == 0) ? 13.f : (shp == 1) ? 30.f : 23.f);
        const float aa = (angi == 0) ? -1.04719755119659775f :
                         (angi == 1) ? -0.52359877559829887f :
                         (angi == 2) ?  0.0f :
                         (angi == 3) ?  0.52359877559829887f :
                         (angi == 4) ?  1.04719755119659775f :
                                        1.57079632679489662f;
        const size_t span = (size_t)b * BPB + ((size_t)(LVOF + ag * GG + p0)) * NCHN;
        #pragma unroll
        for (int h = 0; h < 2; ++h) {
            if ((wid >> 2) == h) {
                #pragma unroll
                for (int j = 0; j < 3; ++j) {
                    const int ch = wn * 48 + j * 16 + lr;
                    if (ch < NCHN) {
                        const float bv = sBias[aL * NCHN + ch];
                        #pragma unroll
                        for (int r = 0; r < 4; ++r) {
                            const int px = wm * 16 + rq + r;       // global px in tile
                            const int pl = px - h * 32;            // 0..31
                            const int p  = p0 + px;
                            const float vv = acc[j][r] + bv;
                            float res;
                            if (ch == 0)      res = (sigm(vv) * sxy - sxy_off + (float)(p & ((1 << Gsh) - 1))) * sf;
                            else if (ch == 1) res = (sigm(vv) * sxy - sxy_off + (float)(p >> Gsh)) * sf;
                            else if (ch == 2) res = __expf(vv) * aw;
                            else if (ch == 3) res = __expf(vv) * ah;
                            else if (ch == 4) res = vv + aa;
                            else              res = sigm(vv);
                            sImg[pl * NCHN + ch] = res;
                        }
                    }
                }
            }
            asm volatile("s_waitcnt lgkmcnt(0)" ::: "memory");
            __builtin_amdgcn_sched_barrier(0);
            __builtin_amdgcn_s_barrier();
            const size_t base = span + (size_t)h * 32 * NCHN;
            #pragma unroll
            for (int k = 0; k < 2; ++k) {
                const int f4 = tid + k * 512;
                if (f4 < 688) {
                    const f32x4 vv = *(const f32x4*)&sImg[f4 * 4];
                    __builtin_nontemporal_store(vv, (f32x4*)&out[base + (size_t)f4 * 4]);
                }
            }
            __builtin_amdgcn_s_barrier();
        }
        #pragma unroll
        for (int j = 0; j < 3; ++j) acc[j] = f32x4{0.f, 0.f, 0.f, 0.f};
    };

    // ---- prologue: bias -> LDS, A half0, B s=0,1; full drain ----
    {
        float bv0 = bias[aBase * NCHN + tid];            // tid < 516 always (512)
        sBias[tid] = bv0;
        if (tid < 4) sBias[512 + tid] = bias[aBase * NCHN + 512 + tid];
    }
    stageA(0);
    stageB(0);
    stageB(1);
    asm volatile("s_waitcnt vmcnt(0) lgkmcnt(0)" ::: "memory");
    __builtin_amdgcn_sched_barrier(0);
    __builtin_amdgcn_s_barrier();

    // ---- main loop ----
    for (int aL = 0; aL < 6; ++aL) {
        for (int kt = 0; kt < KT; ++kt) {
            const int s = aL * KT + kt;
            // exact per-wave wait (in-order vmcnt retirement)
            int wn_;
            if (s >= S - 1)      wn_ = 0;                         // tail
            else if (kt == 0) {
                if (aL == 0)     wn_ = 0;                         // prologue-drained
                else if (!LVL)   wn_ = (wid < 3) ? 6 : (wid < 4) ? 4 : 3;
                else             wn_ = (wid < 3) ? 10 : (wid < 4) ? 8 : 7;
            } else               wn_ = (wid < 4) ? 2 : 1;
            waitv(wn_);
            __builtin_amdgcn_s_barrier();                         // buf(s) ready for all waves
            compute(s & 1, kt);
            __builtin_amdgcn_s_barrier();                         // all done reading buf(s)
            if (kt == KT - 1) {
                if (LVL && aL < 5) stageA(0);                     // next anchor half0
                epilogue(aL);
            } else if (LVL && kt == 3) {
                stageA(1);                                        // half-K restage
            }
            if (s + 2 < S) stageB(s + 2);
        }
    }
}

__global__ __launch_bounds__(512, 2) void detect_gemm(
    const unsigned short* __restrict__ Xb0, const unsigned short* __restrict__ Xb1,
    const unsigned short* __restrict__ Wb0, const unsigned short* __restrict__ Wb1,
    const float* __restrict__ b0, const float* __restrict__ b1,
    float* __restrict__ out)
{
    __shared__ __attribute__((aligned(128))) char smem[70656];
    // XCD swizzle: 1920 = 8 * 240 (bijective); same-mtile groups adjacent per XCD.
    const int bid = blockIdx.x;
    const int v   = (bid & 7) * 240 + (bid >> 3);
    if (v < 1536) body<0>(v,        smem, Xb0, Wb0, b0, out);
    else          body<1>(v - 1536, smem, Xb1, Wb1, b1, out);
}

extern "C" void kernel_launch(void* const* d_in, const int* in_sizes, int n_in,
                              void* d_out, int out_size, void* d_ws, size_t ws_size,
                              hipStream_t stream) {
    const float* x0 = (const float*)d_in[0];
    const float* x1 = (const float*)d_in[1];
    const float* W0 = (const float*)d_in[2];
    const float* b0 = (const float*)d_in[3];
    const float* W1 = (const float*)d_in[4];
    const float* b1 = (const float*)d_in[5];
    float* out = (float*)d_out;

    constexpr size_t XB0_OFF = 0;            // 8*4096*256*2  = 16777216
    constexpr size_t XB1_OFF = 16777216;     // 8*1024*512*2  =  8388608
    constexpr size_t WB0_OFF = 25165824;     // 1548*256*2    =   792576
    constexpr size_t WB1_OFF = 25958400;     // 1548*512*2    =  1585152

    unsigned short* Xb0 = (unsigned short*)((char*)d_ws + XB0_OFF);
    unsigned short* Xb1 = (unsigned short*)((char*)d_ws + XB1_OFF);
    unsigned short* Wb0 = (unsigned short*)((char*)d_ws + WB0_OFF);
    unsigned short* Wb1 = (unsigned short*)((char*)d_ws + WB1_OFF);

    hipLaunchKernelGGL(conv_w_kernel, dim3((297216 + 255) / 256), dim3(256), 0, stream,
                       W0, Wb0, W1, Wb1);
    hipLaunchKernelGGL(transpose_x_kernel, dim3(64, 4, 8), dim3(256), 0, stream,
                       x0, Xb0, 256, 4096);
    hipLaunchKernelGGL(transpose_x_kernel, dim3(16, 8, 8), dim3(256), 0, stream,
                       x1, Xb1, 512, 1024);

    // 512 lvl0-mtiles(64px)*3 grp + 128 lvl1-mtiles(64px)*3 grp = 1920 blocks
    hipLaunchKernelGGL(detect_gemm, dim3(1920), dim3(512), 0, stream,
                       Xb0, Xb1, Wb0, Wb1, b0, b1, out);
}

// Round 16
// 147.187 us; speedup vs baseline: 1.6575x; 1.6575x over previous
//
#include <hip/hip_runtime.h>
#include <hip/hip_bf16.h>

// Detect head: prep (fp32->bf16 convert + x transpose) then fused MFMA GEMM + decode.
// R16 = R12 (best: 148.6us) + T5 s_setprio around MFMA cluster + exact-trip store
// loop. Everything else byte-identical to R12:
//   256-thread blocks, 4 waves (2m x 2n), per-wave 32px x 48ch, acc[2][3].
//   BM=64 x BN=96 anchor tile, BK=64 dbuf + 2-phase prefetch, gload_lds w/ XOR
//   swizzle, mtile-major XCD swizzle, LDS-image epilogue + nt float4 stores.
//   40KB LDS -> 4 blocks/CU (the empirically-required occupancy).

typedef __attribute__((ext_vector_type(8))) short short8;
typedef __attribute__((ext_vector_type(4))) short short4v;
typedef __attribute__((ext_vector_type(4))) float f32x4;
typedef unsigned int u32;

__device__ __forceinline__ unsigned short f2bf(float f) {
    union { float f; unsigned u; } c; c.f = f;
    return (unsigned short)((c.u + 0x7fffu + ((c.u >> 16) & 1u)) >> 16);  // RTNE
}
__device__ __forceinline__ float sigm(float v) {
    return 1.0f / (1.0f + __expf(-v));
}
__device__ __forceinline__ void gload16(const void* g, void* l) {
    __builtin_amdgcn_global_load_lds(
        (const __attribute__((address_space(1))) u32*)g,
        (__attribute__((address_space(3))) u32*)l, 16, 0, 0);
}

#define OUT_CH 1548
#define NCHN   86
#define BPB    7925760   // per-batch output elements = 92160*86

// ---------------- prep kernels ----------------

__global__ void conv_w_kernel(const float* __restrict__ W0, unsigned short* __restrict__ Wb0,
                              const float* __restrict__ W1, unsigned short* __restrict__ Wb1) {
    int i = blockIdx.x * blockDim.x + threadIdx.x;
    if (i >= 297216) return;
    const float* W = W0;
    unsigned short* Wb = Wb0;
    if (i >= 99072) { W = W1; Wb = Wb1; i -= 99072; }
    const float4 f = ((const float4*)W)[i];
    short4v v;
    v[0] = (short)f2bf(f.x); v[1] = (short)f2bf(f.y);
    v[2] = (short)f2bf(f.z); v[3] = (short)f2bf(f.w);
    ((short4v*)Wb)[i] = v;
}

// x [B][C][GG] fp32 -> Xb [B][GG][C] bf16 (64x64 LDS tile transpose)
__global__ void transpose_x_kernel(const float* __restrict__ X, unsigned short* __restrict__ Xb,
                                   int C, int GG) {
    __shared__ float sT[64][65];
    const int p0 = blockIdx.x * 64;
    const int c0 = blockIdx.y * 64;
    const int b  = blockIdx.z;
    const int tid = threadIdx.x;
    const float* src = X + ((size_t)b * C + c0) * GG + p0;
    const int rc = tid >> 4;
    const int cp = (tid & 15) * 4;
    #pragma unroll
    for (int rr = 0; rr < 4; ++rr) {
        const int c = rc + rr * 16;
        const float4 f = *(const float4*)&src[(size_t)c * GG + cp];
        sT[c][cp + 0] = f.x; sT[c][cp + 1] = f.y;
        sT[c][cp + 2] = f.z; sT[c][cp + 3] = f.w;
    }
    __syncthreads();
    const int p  = tid >> 2;
    const int cg = (tid & 3) * 16;
    unsigned short u[16];
    #pragma unroll
    for (int k = 0; k < 16; ++k) u[k] = f2bf(sT[cg + k][p]);
    unsigned short* dst = Xb + ((size_t)b * GG + p0 + p) * C + c0 + cg;
    *(short8*)dst       = *(const short8*)&u[0];
    *(short8*)(dst + 8) = *(const short8*)&u[8];
}

// ---------------- main GEMM + decode ----------------

__global__ __launch_bounds__(256, 4) void detect_gemm(
    const unsigned short* __restrict__ Xb0, const unsigned short* __restrict__ Xb1,
    const unsigned short* __restrict__ Wb0, const unsigned short* __restrict__ Wb1,
    const float* __restrict__ b0, const float* __restrict__ b1,
    float* __restrict__ out)
{
    // LDS 40KB: sA dbuf 2x8KB + sB dbuf 2x12KB; epilogue reuses as flat
    // [64*86] fp32 image (22KB). 4 blocks/CU.
    __shared__ __attribute__((aligned(128))) char smem[40960];
    unsigned short* sAbase = (unsigned short*)smem;               // 2 x 4096 elems
    unsigned short* sBbase = (unsigned short*)(smem + 16384);     // 2 x 6144 elems
    float* sOutF = (float*)smem;

    // XCD swizzle (mtile-major): 11520 = 8 * 1440; consecutive v within an XCD
    // share the same mtile across 18 anchors -> A-tile L2-hit 17x.
    const int bid = blockIdx.x;
    const int v   = (bid & 7) * 1440 + (bid >> 3);
    const int mt  = v / 18;           // mtile 0..639
    const int a   = v - mt * 18;      // anchor 0..17

    const bool lvl1 = (mt >= 512);
    const unsigned short* __restrict__ Xb = lvl1 ? Xb1 : Xb0;
    const unsigned short* __restrict__ Wb = lvl1 ? Wb1 : Wb0;
    const float* __restrict__ biasA = (lvl1 ? b1 : b0) + a * NCHN;
    const int C   = lvl1 ? 512 : 256;
    const int GG  = lvl1 ? 1024 : 4096;
    const int Gsh = lvl1 ? 5 : 6;
    const float sxy     = lvl1 ? 1.1f : 1.2f;
    const float sxy_off = (sxy - 1.0f) * 0.5f;
    const float sf      = lvl1 ? 16.0f : 8.0f;
    const int shp  = a / 6;
    const int angi = a - shp * 6;
    const float aw = lvl1 ? ((shp == 0) ? 30.f : (shp == 1) ? 62.f : 59.f)
                          : ((shp == 0) ? 10.f : (shp == 1) ? 16.f : 33.f);
    const float ah = lvl1 ? ((shp == 0) ? 61.f : (shp == 1) ? 45.f : 119.f)
                          : ((shp == 0) ? 13.f : (shp == 1) ? 30.f : 23.f);
    const float aa = (angi == 0) ? -1.04719755119659775f :
                     (angi == 1) ? -0.52359877559829887f :
                     (angi == 2) ?  0.0f :
                     (angi == 3) ?  0.52359877559829887f :
                     (angi == 4) ?  1.04719755119659775f :
                                    1.57079632679489662f;

    const int tloc = lvl1 ? (mt - 512) : mt;
    const int b  = tloc >> (lvl1 ? 4 : 6);               // tiles/img: 16 / 64
    const int p0 = (tloc & ((lvl1 ? 16 : 64) - 1)) * 64; // pixel offset

    const unsigned short* __restrict__ Xp = Xb + ((size_t)b * GG + p0) * C;

    const int tid  = threadIdx.x;
    const int lane = tid & 63;
    const int wid  = tid >> 6;        // 0..3
    const int wm = wid >> 1;          // 0..1 : 32-pixel slice
    const int wn = wid & 1;           // 0..1 : 48-channel half

    f32x4 acc[2][3];
    #pragma unroll
    for (int i = 0; i < 2; ++i)
        #pragma unroll
        for (int j = 0; j < 3; ++j)
            acc[i][j] = f32x4{0.f, 0.f, 0.f, 0.f};

    // staging geometry: chunk c covers 8 rows (1KB, 128B row pitch); lane
    // covers base + lane*16 (HW rule). Source col pre-swizzled so the linear
    // LDS image is XOR-swizzled.
    const int rowIn = lane >> 3;                                  // 0..7
    const int scolE = ((((lane & 7) << 4)) ^ (rowIn << 4)) >> 1;  // element col in source

    const int lr   = lane & 15;
    const int kqb  = (lane >> 4) << 4;        // k-quarter byte offset in 64B half-row
    const int swzR = (lr & 7) << 4;           // read-side XOR

    const int KT = C >> 6;

    auto stage = [&](int bufsel, int kt) {
        const int k0 = kt << 6;
        unsigned short* sA = sAbase + bufsel * 4096;
        unsigned short* sB = sBbase + bufsel * 6144;
        // A: 8KB = 2 issues x 4KB (chunks c = i*4+wid, rows c*8+rowIn = 0..63)
        #pragma unroll
        for (int i = 0; i < 2; ++i) {
            const int c = i * 4 + wid;
            const int row = c * 8 + rowIn;
            gload16(Xp + (size_t)row * C + k0 + scolE, (char*)sA + (c << 10));
        }
        // B: 12KB = 3 issues x 4KB (chunks c = j*4+wid, rows 0..95 exactly)
        #pragma unroll
        for (int j = 0; j < 3; ++j) {
            const int c = j * 4 + wid;
            const int row = c * 8 + rowIn;
            int grow = a * NCHN + row;
            grow = grow > (OUT_CH - 1) ? (OUT_CH - 1) : grow;
            gload16(Wb + (size_t)grow * C + k0 + scolE, (char*)sB + (c << 10));
        }
    };

    auto compute = [&](int bufsel) {
        const char* sA = (const char*)(sAbase + bufsel * 4096);
        const char* sB = (const char*)(sBbase + bufsel * 6144);
        #pragma unroll
        for (int kk = 0; kk < 2; ++kk) {
            const int cb = (kk << 6) + kqb;
            short8 af[2], bfr[3];
            #pragma unroll
            for (int i = 0; i < 2; ++i) {
                const int ra = wm * 32 + i * 16 + lr;
                af[i] = *(const short8*)(sA + ra * 128 + (cb ^ swzR));
            }
            #pragma unroll
            for (int j = 0; j < 3; ++j) {
                const int rb = wn * 48 + j * 16 + lr;
                bfr[j] = *(const short8*)(sB + rb * 128 + (cb ^ swzR));
            }
            // T5: bias the CU scheduler toward this wave's MFMA burst while
            // other (phase-shifted) blocks' waves issue staging/epilogue VMEM.
            __builtin_amdgcn_s_setprio(1);
            #pragma unroll
            for (int i = 0; i < 2; ++i)
                #pragma unroll
                for (int j = 0; j < 3; ++j)
                    acc[i][j] = __builtin_amdgcn_mfma_f32_16x16x32_bf16(af[i], bfr[j], acc[i][j], 0, 0, 0);
            __builtin_amdgcn_s_setprio(0);
        }
    };

    // prologue + 2-phase pipelined K loop (issue next-tile loads BEFORE compute)
    stage(0, 0);
    __syncthreads();
    int cur = 0;
    for (int kt = 0; kt < KT; ++kt) {
        if (kt + 1 < KT) stage(cur ^ 1, kt + 1);
        compute(cur);
        __syncthreads();          // drains this iteration's prefetch loads too
        cur ^= 1;
    }

    // ---- epilogue: decode into flat LDS image [64 px][86 ch], then stream out ----
    // C/D layout: col(N)=lane&15, row(M)=(lane>>4)*4+reg
    const int rq = (lane >> 4) * 4;
    const int lvloff = lvl1 ? 73728 : 0;

    #pragma unroll
    for (int j = 0; j < 3; ++j) {
        const int ch = wn * 48 + j * 16 + lr;
        if (ch < NCHN) {
            const float bv = biasA[ch];
            #pragma unroll
            for (int i = 0; i < 2; ++i) {
                #pragma unroll
                for (int r = 0; r < 4; ++r) {
                    const int px = wm * 32 + i * 16 + rq + r;   // 0..63
                    const int p  = p0 + px;                     // pixel in level grid
                    const float vv = acc[i][j][r] + bv;
                    float res;
                    if (ch == 0)      res = (sigm(vv) * sxy - sxy_off + (float)(p & ((1 << Gsh) - 1))) * sf;
                    else if (ch == 1) res = (sigm(vv) * sxy - sxy_off + (float)(p >> Gsh)) * sf;
                    else if (ch == 2) res = __expf(vv) * aw;
                    else if (ch == 3) res = __expf(vv) * ah;
                    else if (ch == 4) res = vv + aa;
                    else              res = sigm(vv);
                    sOutF[px * NCHN + ch] = res;
                }
            }
        }
    }
    __syncthreads();

    // stream out: block span = 64*86 = 5504 dwords = 1376 float4, contiguous &
    // 16B-aligned. Non-temporal (write-once, bypass L2 allocation).
    // Exact trip counts: 5 full iterations of 256 + 96 remainder.
    const size_t spanDw = (size_t)b * BPB + ((size_t)(lvloff + a * GG + p0)) * NCHN;
    #pragma unroll
    for (int k = 0; k < 5; ++k) {
        const int f4 = tid + k * 256;
        const f32x4 vv = *(const f32x4*)&sOutF[f4 * 4];
        __builtin_nontemporal_store(vv, (f32x4*)&out[spanDw + f4 * 4]);
    }
    if (tid < 96) {
        const int f4 = tid + 1280;
        const f32x4 vv = *(const f32x4*)&sOutF[f4 * 4];
        __builtin_nontemporal_store(vv, (f32x4*)&out[spanDw + f4 * 4]);
    }
}

extern "C" void kernel_launch(void* const* d_in, const int* in_sizes, int n_in,
                              void* d_out, int out_size, void* d_ws, size_t ws_size,
                              hipStream_t stream) {
    const float* x0 = (const float*)d_in[0];
    const float* x1 = (const float*)d_in[1];
    const float* W0 = (const float*)d_in[2];
    const float* b0 = (const float*)d_in[3];
    const float* W1 = (const float*)d_in[4];
    const float* b1 = (const float*)d_in[5];
    float* out = (float*)d_out;

    constexpr size_t XB0_OFF = 0;            // 8*4096*256*2  = 16777216
    constexpr size_t XB1_OFF = 16777216;     // 8*1024*512*2  =  8388608
    constexpr size_t WB0_OFF = 25165824;     // 1548*256*2    =   792576
    constexpr size_t WB1_OFF = 25958400;     // 1548*512*2    =  1585152

    unsigned short* Xb0 = (unsigned short*)((char*)d_ws + XB0_OFF);
    unsigned short* Xb1 = (unsigned short*)((char*)d_ws + XB1_OFF);
    unsigned short* Wb0 = (unsigned short*)((char*)d_ws + WB0_OFF);
    unsigned short* Wb1 = (unsigned short*)((char*)d_ws + WB1_OFF);

    hipLaunchKernelGGL(conv_w_kernel, dim3((297216 + 255) / 256), dim3(256), 0, stream,
                       W0, Wb0, W1, Wb1);
    hipLaunchKernelGGL(transpose_x_kernel, dim3(64, 4, 8), dim3(256), 0, stream,
                       x0, Xb0, 256, 4096);
    hipLaunchKernelGGL(transpose_x_kernel, dim3(16, 8, 8), dim3(256), 0, stream,
                       x1, Xb1, 512, 1024);

    // 640 mtiles (512 lvl0 + 128 lvl1) x 18 anchors = 11520 blocks
    hipLaunchKernelGGL(detect_gemm, dim3(11520), dim3(256), 0, stream,
                       Xb0, Xb1, Wb0, Wb1, b0, b1, out);
}